// Round 11
// baseline (197.718 us; speedup 1.0000x reference)
//
#include <hip/hip_runtime.h>
#include <stdint.h>

#define D_MODEL 1024
#define SEQ     2048
#define BATCH   4
#define NHEADS  16
#define HDIM    64
#define NBH     (BATCH*NHEADS)   // 64
#define MROWS   (BATCH*SEQ)      // 8192

typedef _Float16 half_t;
typedef __attribute__((ext_vector_type(8))) _Float16 half8;
typedef __attribute__((ext_vector_type(4))) _Float16 half4;
typedef __attribute__((ext_vector_type(2))) __fp16 fp16x2;
typedef __attribute__((ext_vector_type(4))) float f32x4;
typedef __attribute__((ext_vector_type(16))) float f32x16;

typedef const __attribute__((address_space(1))) void* gas_ptr;
typedef __attribute__((address_space(3))) void* las_ptr;

__device__ __forceinline__ void g2l16(const half_t* g, half_t* l) {
  __builtin_amdgcn_global_load_lds((gas_ptr)g, (las_ptr)l, 16, 0, 0);
}

__device__ __forceinline__ uint32_t pk16(float a, float b) {
  fp16x2 h = __builtin_amdgcn_cvt_pkrtz(a, b);
  return __builtin_bit_cast(uint32_t, h);
}

#define BARM()       do { asm volatile("" ::: "memory");                   \
                          __builtin_amdgcn_s_barrier();                    \
                          __builtin_amdgcn_sched_barrier(0);               \
                          asm volatile("" ::: "memory"); } while (0)
#define VM8()        do { asm volatile("s_waitcnt vmcnt(8)" ::: "memory"); \
                          __builtin_amdgcn_sched_barrier(0); } while (0)
#define VM0()        do { asm volatile("s_waitcnt vmcnt(0)" ::: "memory"); \
                          __builtin_amdgcn_sched_barrier(0); } while (0)

// attn phase macros (counted depth-2)
#define WAIT4_BAR()  do { asm volatile("s_waitcnt vmcnt(4)" ::: "memory"); \
                          __builtin_amdgcn_sched_barrier(0);               \
                          __builtin_amdgcn_s_barrier();                    \
                          __builtin_amdgcn_sched_barrier(0); } while (0)
#define WAIT0_BAR()  do { asm volatile("s_waitcnt vmcnt(0)" ::: "memory"); \
                          __builtin_amdgcn_sched_barrier(0);               \
                          __builtin_amdgcn_s_barrier();                    \
                          __builtin_amdgcn_sched_barrier(0); } while (0)
#define POST_BAR()   do { __builtin_amdgcn_s_barrier();                    \
                          __builtin_amdgcn_sched_barrier(0); } while (0)

// ---------------- fused fp32 -> fp16 conversion ----------------
#define N4_X   (MROWS*D_MODEL/4)
#define N4_WQ  (3*D_MODEL*D_MODEL/4)
#define N4_WO  (D_MODEL*D_MODEL/4)
#define N4_TOT (N4_X+N4_WQ+N4_WO)

__global__ __launch_bounds__(256) void k_cvt3(const float* __restrict__ x,
                                              const float* __restrict__ wq,
                                              const float* __restrict__ wo,
                                              half_t* __restrict__ dst) {
  for (int i = blockIdx.x * 256 + threadIdx.x; i < N4_TOT; i += 2048 * 256) {
    const float* s;
    int j = i;
    if (j < N4_X) { s = x; }
    else if (j < N4_X + N4_WQ) { s = wq; j -= N4_X; }
    else { s = wo; j -= N4_X + N4_WQ; }
    float4 v = reinterpret_cast<const float4*>(s)[j];
    half4 o = {(_Float16)v.x, (_Float16)v.y, (_Float16)v.z, (_Float16)v.w};
    *reinterpret_cast<half4*>(dst + (size_t)i * 4) = o;
  }
}

// ---------------- GEMM1: 256x256, BK=64, 8 waves, 4 sub-phases/K-tile ----------------
// LDS element (r,c): r*64 + ((c>>3)^(r&7))*8 + (c&7). Staged with pre-swizzled source.
#define QBM 256
#define QBN 256
#define QBK 64
#define QNT (D_MODEL/QBK)   // 16

__global__ __launch_bounds__(512) void k_gemm_qkv(
    const half_t* __restrict__ A,    // [8192][1024]
    const half_t* __restrict__ W,    // [3072][1024]
    const float*  __restrict__ bias, // [3072]
    half_t* __restrict__ Qo,         // [64][2048][64]
    half_t* __restrict__ Ko,         // [64][2048][64]
    half_t* __restrict__ VTo)        // [64][64][2048]
{
  constexpr int K = D_MODEL;
  __shared__ __align__(16) half_t SA[2][QBM * QBK];   // 2 x 32 KB
  __shared__ __align__(16) half_t SB[2][QBN * QBK];   // 2 x 32 KB

  const int tid = threadIdx.x;
  const int wid = tid >> 6, lane = tid & 63;
  const int wr = wid >> 2;          // 0..1  (M half: 128 rows)
  const int wn = wid & 3;           // 0..3  (N quarter: 64 cols)
  const int lg = lane >> 4, lq = lane & 15;
  const int m0 = blockIdx.x * QBM, n0 = blockIdx.y * QBN;

  f32x4 acc[8][4] = {};

  // staging: instr i covers rows i*64+(tid>>3), chunk tid&7, source pre-swizzled
  const int srow = tid >> 3;        // 0..63
  const int swc  = ((tid & 7) ^ (srow & 7)) * 8;
  const half_t* Ag = A + (size_t)(m0 + srow) * K + swc;
  const half_t* Wg = W + (size_t)(n0 + srow) * K + swc;
  const int wb = wid * 512;         // dest offset within 64-row section (halfs)

  auto stageA = [&](int kt, int buf) {
#pragma unroll
    for (int i = 0; i < 4; ++i)
      g2l16(Ag + (size_t)(i * 64) * K + kt * QBK, &SA[buf][i * 4096 + wb]);
  };
  auto stageB = [&](int kt, int buf) {
#pragma unroll
    for (int i = 0; i < 4; ++i)
      g2l16(Wg + (size_t)(i * 64) * K + kt * QBK, &SB[buf][i * 4096 + wb]);
  };

  // prologue: tiles 0 and 1 fully staged (16 loads/wave in flight)
  stageA(0, 0); stageB(0, 0);
  stageA(1, 1); stageB(1, 1);

  half8 af[4][2], bf[4][2];
  for (int kt = 0; kt < QNT; ++kt) {
    const int buf = kt & 1;
    // tile-kt boundary: only tile kt+1's (and later kt+2's) 8 loads may stay in flight
    if (kt < QNT - 1) { VM8(); } else { VM0(); }
    BARM();
    const half_t* sa = &SA[buf][0];
    const half_t* sb = &SB[buf][0];

    // ---- phase 0: read A m0-3 + B n0-1; MFMA (m0-3 x n0-1) ----
#pragma unroll
    for (int mt = 0; mt < 4; ++mt) {
      const int row = wr * 128 + mt * 16 + lq;
#pragma unroll
      for (int ks = 0; ks < 2; ++ks)
        af[mt][ks] = *(const half8*)(sa + row * 64 + (((ks << 2) + lg) ^ (lq & 7)) * 8);
    }
#pragma unroll
    for (int nt = 0; nt < 2; ++nt) {
      const int row = wn * 64 + nt * 16 + lq;
#pragma unroll
      for (int ks = 0; ks < 2; ++ks)
        bf[nt][ks] = *(const half8*)(sb + row * 64 + (((ks << 2) + lg) ^ (lq & 7)) * 8);
    }
    __builtin_amdgcn_s_setprio(1);
#pragma unroll
    for (int mt = 0; mt < 4; ++mt)
#pragma unroll
      for (int nt = 0; nt < 2; ++nt)
#pragma unroll
        for (int ks = 0; ks < 2; ++ks)
          acc[mt][nt] = __builtin_amdgcn_mfma_f32_16x16x32_f16(af[mt][ks], bf[nt][ks], acc[mt][nt], 0, 0, 0);
    __builtin_amdgcn_s_setprio(0);
    BARM();

    // ---- phase 1: read B n2-3; MFMA (m0-3 x n2-3) ----
#pragma unroll
    for (int nt = 2; nt < 4; ++nt) {
      const int row = wn * 64 + nt * 16 + lq;
#pragma unroll
      for (int ks = 0; ks < 2; ++ks)
        bf[nt][ks] = *(const half8*)(sb + row * 64 + (((ks << 2) + lg) ^ (lq & 7)) * 8);
    }
    __builtin_amdgcn_s_setprio(1);
#pragma unroll
    for (int mt = 0; mt < 4; ++mt)
#pragma unroll
      for (int nt = 2; nt < 4; ++nt)
#pragma unroll
        for (int ks = 0; ks < 2; ++ks)
          acc[mt][nt] = __builtin_amdgcn_mfma_f32_16x16x32_f16(af[mt][ks], bf[nt][ks], acc[mt][nt], 0, 0, 0);
    __builtin_amdgcn_s_setprio(0);
    BARM();

    // ---- phase 2: read A m4-7 (overwrites af); MFMA (m4-7 x n2-3) ----
#pragma unroll
    for (int mt = 0; mt < 4; ++mt) {
      const int row = wr * 128 + (mt + 4) * 16 + lq;
#pragma unroll
      for (int ks = 0; ks < 2; ++ks)
        af[mt][ks] = *(const half8*)(sa + row * 64 + (((ks << 2) + lg) ^ (lq & 7)) * 8);
    }
    __builtin_amdgcn_s_setprio(1);
#pragma unroll
    for (int mt = 0; mt < 4; ++mt)
#pragma unroll
      for (int nt = 2; nt < 4; ++nt)
#pragma unroll
        for (int ks = 0; ks < 2; ++ks)
          acc[mt + 4][nt] = __builtin_amdgcn_mfma_f32_16x16x32_f16(af[mt][ks], bf[nt][ks], acc[mt + 4][nt], 0, 0, 0);
    __builtin_amdgcn_s_setprio(0);
    BARM();   // all reads of buf done block-wide

    // ---- phase 3: stage tile kt+2 into this buffer; MFMA (m4-7 x n0-1) ----
    if (kt + 2 < QNT) { stageA(kt + 2, buf); stageB(kt + 2, buf); }
    __builtin_amdgcn_s_setprio(1);
#pragma unroll
    for (int mt = 0; mt < 4; ++mt)
#pragma unroll
      for (int nt = 0; nt < 2; ++nt)
#pragma unroll
        for (int ks = 0; ks < 2; ++ks)
          acc[mt + 4][nt] = __builtin_amdgcn_mfma_f32_16x16x32_f16(af[mt][ks], bf[nt][ks], acc[mt + 4][nt], 0, 0, 0);
    __builtin_amdgcn_s_setprio(0);
    // loop-top vmcnt+barrier closes the tile
  }

  // ---- epilogue: scatter Q/K/VT ----
  const int sec   = n0 >> 10;
  const int csec0 = n0 & 1023;
#pragma unroll
  for (int mt = 0; mt < 8; ++mt) {
#pragma unroll
    for (int nt = 0; nt < 4; ++nt) {
      const int n  = n0 + wn * 64 + nt * 16 + lq;
      const float bv = bias[n];
      const int c = csec0 + wn * 64 + nt * 16 + lq;
      const int h = c >> 6, d = c & 63;
#pragma unroll
      for (int r = 0; r < 4; ++r) {
        const int m = m0 + wr * 128 + mt * 16 + lg * 4 + r;
        const int b = m >> 11, s = m & 2047;
        const half_t val = (half_t)(acc[mt][nt][r] + bv);
        const int bhh = (b << 4) + h;
        if (sec == 0)      Qo[((size_t)bhh * SEQ + s) * HDIM + d] = val;
        else if (sec == 1) Ko[((size_t)bhh * SEQ + s) * HDIM + d] = val;
        else               VTo[((size_t)bhh * HDIM + d) * SEQ + s] = val;
      }
    }
  }
}

// ---------------- flash attention (causal), balanced pairs + counted-vmcnt dbuf ----
__global__ __launch_bounds__(256) void k_attn(
    const half_t* __restrict__ Q,   // [64][2048][64]
    const half_t* __restrict__ Kt,  // [64][2048][64]
    const half_t* __restrict__ Vt,  // [64][64][2048]  (V transposed)
    half_t* __restrict__ O)         // [8192][1024]
{
  const int n    = blockIdx.x;                  // 0..511
  const int bh   = (n & 7) * 8 + ((n >> 3) & 7);// head-block: 8 heads per XCD
  const int pg   = n >> 6;                      // 0..7 pair-group
  const int wave = threadIdx.x >> 6, lane = threadIdx.x & 63;
  const int ql   = lane & 31, hi = lane >> 5;
  const int tid  = threadIdx.x;

  __shared__ __align__(16) half_t KS[2][64 * 64];
  __shared__ __align__(16) half_t VS[2][64 * 64];

  const half_t* Qh = Q  + (size_t)bh * SEQ * HDIM;
  const half_t* Kh = Kt + (size_t)bh * SEQ * HDIM;
  const half_t* Vh = Vt + (size_t)bh * HDIM * SEQ;
  const int bb = bh >> 4, hh = bh & 15;

  const int sr0  = tid >> 3;                    // 0..31
  const int sc16 = tid & 7;
  const int sw8  = (sc16 ^ (sr0 & 7)) << 3;     // swizzled chunk offset (halfs)
  const size_t ksrc = (size_t)sr0 * HDIM + sw8;
  const size_t vsrc = (size_t)sr0 * SEQ  + sw8;
  const int xw = ql & 7;                        // read-side row XOR key

  auto stageKV = [&](int kt, int buf) {
    const half_t* kg = Kh + (size_t)kt * 64 * HDIM + ksrc;
    const half_t* vg = Vh + kt * 64 + vsrc;
    g2l16(kg,                    &KS[buf][wave * 512]);
    g2l16(kg + 32 * HDIM,        &KS[buf][2048 + wave * 512]);
    g2l16(vg,                    &VS[buf][wave * 512]);
    g2l16(vg + (size_t)32 * SEQ, &VS[buf][2048 + wave * 512]);
  };

  for (int ph = 0; ph < 2; ++ph) {
    const int j   = ph ? 63 - (pg * 4 + wave) : pg * 4 + wave;   // q-tile (32 rows)
    const int NT  = ph ? 32 - 2 * pg : 2 * pg + 2;               // block-uniform, >=2
    const int ktd = j >> 1;                                      // my last k-tile
    const int qg  = j * 32 + ql;                                 // my q-row

    half8 qf[4];
    {
      const half_t* Qp = Qh + (size_t)qg * HDIM + hi * 8;
      const _Float16 qs = (_Float16)0.125f;
#pragma unroll
      for (int kk = 0; kk < 4; ++kk) {
        half8 t = *(const half8*)(Qp + kk * 16);
        qf[kk] = t * qs;
      }
    }

    f32x16 acc[2] = {};
    float mrun = -1e30f, lrun = 0.f;

    stageKV(0, 0);
    stageKV(1, 1);

    int cur = 0;
    for (int kt = 0; kt < NT; ++kt) {
      if (kt + 1 < NT) WAIT4_BAR(); else WAIT0_BAR();

      if (kt <= ktd) {
        f32x16 sc[2] = {};
        const half_t* Kl = &KS[cur][0];
#pragma unroll
        for (int kk = 0; kk < 4; ++kk) {
          const int c = ((kk * 2 + hi) ^ xw) << 3;
          half8 k0 = *(const half8*)(Kl + ql * 64 + c);
          half8 k1 = *(const half8*)(Kl + (ql + 32) * 64 + c);
          sc[0] = __builtin_amdgcn_mfma_f32_32x32x16_f16(k0, qf[kk], sc[0], 0, 0, 0);
          sc[1] = __builtin_amdgcn_mfma_f32_32x32x16_f16(k1, qf[kk], sc[1], 0, 0, 0);
        }

        half8 vf[2][4];
        const half_t* Vl = &VS[cur][0];
#pragma unroll
        for (int dt = 0; dt < 2; ++dt)
#pragma unroll
          for (int ks = 0; ks < 4; ++ks) {
            const int c = ((ks * 2 + hi) ^ xw) << 3;
            vf[dt][ks] = *(const half8*)(Vl + (dt * 32 + ql) * 64 + c);
          }

        if (kt == ktd) {
#pragma unroll
          for (int t = 0; t < 2; ++t)
#pragma unroll
            for (int r = 0; r < 16; ++r) {
              const int kgl = kt * 64 + t * 32 + (r & 3) + 8 * (r >> 2) + 4 * hi;
              sc[t][r] = (kgl > qg) ? -1e30f : sc[t][r];
            }
        }

        float m0 = -1e30f, m1 = -1e30f, m2 = -1e30f, m3 = -1e30f;
#pragma unroll
        for (int t = 0; t < 2; ++t)
#pragma unroll
          for (int r = 0; r < 16; r += 4) {
            m0 = fmaxf(m0, sc[t][r]);     m1 = fmaxf(m1, sc[t][r + 1]);
            m2 = fmaxf(m2, sc[t][r + 2]); m3 = fmaxf(m3, sc[t][r + 3]);
          }
        float mx = fmaxf(fmaxf(m0, m1), fmaxf(m2, m3));
        mx = fmaxf(mx, __shfl_xor(mx, 32, 64));

        if (!__all(mx - mrun <= 8.f)) {
          const float mnew = fmaxf(mrun, mx);
          const float alpha = __expf(mrun - mnew);
          mrun = mnew;
          lrun *= alpha;
          acc[0] *= alpha;
          acc[1] *= alpha;
        }

        float s0 = 0.f, s1 = 0.f, s2 = 0.f, s3 = 0.f;
#pragma unroll
        for (int t = 0; t < 2; ++t)
#pragma unroll
          for (int r = 0; r < 16; r += 4) {
            sc[t][r]     = __expf(sc[t][r]     - mrun); s0 += sc[t][r];
            sc[t][r + 1] = __expf(sc[t][r + 1] - mrun); s1 += sc[t][r + 1];
            sc[t][r + 2] = __expf(sc[t][r + 2] - mrun); s2 += sc[t][r + 2];
            sc[t][r + 3] = __expf(sc[t][r + 3] - mrun); s3 += sc[t][r + 3];
          }
        float lsum = (s0 + s1) + (s2 + s3);
        lsum += __shfl_xor(lsum, 32, 64);
        lrun += lsum;

#pragma unroll
        for (int ks = 0; ks < 4; ++ks) {
          const int t  = ks >> 1;
          const int r0 = (ks & 1) * 8;
          const uint32_t a0 = pk16(sc[t][r0 + 0], sc[t][r0 + 1]);
          const uint32_t a1 = pk16(sc[t][r0 + 2], sc[t][r0 + 3]);
          const uint32_t a2 = pk16(sc[t][r0 + 4], sc[t][r0 + 5]);
          const uint32_t a3 = pk16(sc[t][r0 + 6], sc[t][r0 + 7]);
          const uint32_t snd0 = hi ? a0 : a2;
          const uint32_t snd1 = hi ? a1 : a3;
          const uint32_t rc0 = (uint32_t)__shfl_xor((int)snd0, 32, 64);
          const uint32_t rc1 = (uint32_t)__shfl_xor((int)snd1, 32, 64);
          union { uint32_t u[4]; half8 h; } fu;
          fu.u[0] = hi ? rc0 : a0;
          fu.u[1] = hi ? rc1 : a1;
          fu.u[2] = hi ? a2  : rc0;
          fu.u[3] = hi ? a3  : rc1;
          acc[0] = __builtin_amdgcn_mfma_f32_32x32x16_f16(vf[0][ks], fu.h, acc[0], 0, 0, 0);
          acc[1] = __builtin_amdgcn_mfma_f32_32x32x16_f16(vf[1][ks], fu.h, acc[1], 0, 0, 0);
        }
      }

      POST_BAR();
      if (kt + 2 < NT) stageKV(kt + 2, cur);
      cur ^= 1;
    }

    const float inv = 1.0f / lrun;
    half_t* Orow = O + ((size_t)bb * SEQ + qg) * D_MODEL + hh * HDIM + hi * 4;
#pragma unroll
    for (int dt = 0; dt < 2; ++dt)
#pragma unroll
      for (int g = 0; g < 4; ++g) {
        half4 o;
#pragma unroll
        for (int jj = 0; jj < 4; ++jj) o[jj] = (_Float16)(acc[dt][g * 4 + jj] * inv);
        *(half4*)(Orow + dt * 32 + g * 8) = o;
      }
  }
}

// ---------------- GEMM2: out = AO @ w_out^T + b_out (fp32 out), 128^2 BK=64 ----------
#define BM 128
#define BN 128
#define BK 64
#define NTK (D_MODEL / BK)   // 16

__global__ __launch_bounds__(256) void k_gemm_out(
    const half_t* __restrict__ A,
    const half_t* __restrict__ W,
    const float*  __restrict__ bias,
    float* __restrict__ C)
{
  constexpr int K = D_MODEL;
  __shared__ __align__(16) half_t As[BM * BK];
  __shared__ __align__(16) half_t Bs[BN * BK];
  const int tid = threadIdx.x;
  const int wid = tid >> 6, lane = tid & 63;
  const int wr = wid >> 1, wc = wid & 1;
  const int lg = lane >> 4, lq = lane & 15;
  const int m0 = blockIdx.x * BM, n0 = blockIdx.y * BN;

  f32x4 acc[4][4] = {};
  const int srow = tid >> 3;
  const int swc  = ((tid & 7) ^ (srow & 7)) * 8;
  const half_t* Ag = A + (size_t)(m0 + srow) * K + swc;
  const half_t* Wg = W + (size_t)(n0 + srow) * K + swc;

  for (int kt = 0; kt < NTK; ++kt) {
    __syncthreads();
#pragma unroll
    for (int i = 0; i < 4; ++i) {
      g2l16(Ag + (size_t)(i * 32) * K + kt * BK, &As[i * 2048 + wid * 512]);
      g2l16(Wg + (size_t)(i * 32) * K + kt * BK, &Bs[i * 2048 + wid * 512]);
    }
    __syncthreads();

    half8 af[2][4], bf[2][4];
#pragma unroll
    for (int ks = 0; ks < 2; ++ks) {
      const int cs = ((ks * 4 + lg) ^ (lq & 7)) * 8;
#pragma unroll
      for (int mt = 0; mt < 4; ++mt)
        af[ks][mt] = *(const half8*)(&As[(wr * 64 + mt * 16 + lq) * 64 + cs]);
#pragma unroll
      for (int nt = 0; nt < 4; ++nt)
        bf[ks][nt] = *(const half8*)(&Bs[(wc * 64 + nt * 16 + lq) * 64 + cs]);
    }
#pragma unroll
    for (int ks = 0; ks < 2; ++ks)
#pragma unroll
      for (int mt = 0; mt < 4; ++mt)
#pragma unroll
        for (int nt = 0; nt < 4; ++nt)
          acc[mt][nt] = __builtin_amdgcn_mfma_f32_16x16x32_f16(af[ks][mt], bf[ks][nt], acc[mt][nt], 0, 0, 0);
  }

#pragma unroll
  for (int mt = 0; mt < 4; ++mt) {
#pragma unroll
    for (int nt = 0; nt < 4; ++nt) {
      const int n = n0 + wc * 64 + nt * 16 + lq;
      const float bv = bias[n];
#pragma unroll
      for (int r = 0; r < 4; ++r) {
        const int m = m0 + wr * 64 + mt * 16 + lg * 4 + r;
        C[(size_t)m * D_MODEL + n] = acc[mt][nt][r] + bv;
      }
    }
  }
}

// ---------------- launch ----------------
extern "C" void kernel_launch(void* const* d_in, const int* in_sizes, int n_in,
                              void* d_out, int out_size, void* d_ws, size_t ws_size,
                              hipStream_t stream) {
  const float* x    = (const float*)d_in[0];
  const float* wqkv = (const float*)d_in[1];
  const float* bqkv = (const float*)d_in[2];
  const float* wout = (const float*)d_in[3];
  const float* bout = (const float*)d_in[4];
  float* out = (float*)d_out;

  char* ws = (char*)d_ws;
  half_t* xb  = (half_t*)ws; ws += (size_t)MROWS * D_MODEL * 2;
  half_t* wqb = (half_t*)ws; ws += (size_t)3 * D_MODEL * D_MODEL * 2;
  half_t* wob = (half_t*)ws; ws += (size_t)D_MODEL * D_MODEL * 2;
  half_t* Qb  = (half_t*)ws; ws += (size_t)NBH * SEQ * HDIM * 2;
  half_t* Kb  = (half_t*)ws; ws += (size_t)NBH * SEQ * HDIM * 2;
  half_t* Vb  = (half_t*)ws; ws += (size_t)NBH * SEQ * HDIM * 2;
  half_t* AO  = (half_t*)ws; ws += (size_t)MROWS * D_MODEL * 2;

  k_cvt3<<<2048, 256, 0, stream>>>(x, wqkv, wout, xb);

  k_gemm_qkv<<<dim3(MROWS / QBM, 3 * D_MODEL / QBN), 512, 0, stream>>>(xb, wqb, bqkv, Qb, Kb, Vb);
  k_attn<<<dim3(512), 256, 0, stream>>>(Qb, Kb, Vb, AO);
  k_gemm_out<<<dim3(MROWS / BM, D_MODEL / BN), 256, 0, stream>>>(AO, wob, bout, out);
}

// Round 12
// 184.756 us; speedup vs baseline: 1.0702x; 1.0702x over previous
//
#include <hip/hip_runtime.h>
#include <stdint.h>

#define D_MODEL 1024
#define SEQ     2048
#define BATCH   4
#define NHEADS  16
#define HDIM    64
#define NBH     (BATCH*NHEADS)   // 64
#define MROWS   (BATCH*SEQ)      // 8192

typedef _Float16 half_t;
typedef __attribute__((ext_vector_type(8))) _Float16 half8;
typedef __attribute__((ext_vector_type(4))) _Float16 half4;
typedef __attribute__((ext_vector_type(2))) __fp16 fp16x2;
typedef __attribute__((ext_vector_type(4))) float f32x4;
typedef __attribute__((ext_vector_type(16))) float f32x16;

typedef const __attribute__((address_space(1))) void* gas_ptr;
typedef __attribute__((address_space(3))) void* las_ptr;

// async global->LDS, 16B per lane; LDS dest = wave-uniform base + lane*16
__device__ __forceinline__ void g2l16(const half_t* g, half_t* l) {
  __builtin_amdgcn_global_load_lds((gas_ptr)g, (las_ptr)l, 16, 0, 0);
}

__device__ __forceinline__ uint32_t pk16(float a, float b) {
  fp16x2 h = __builtin_amdgcn_cvt_pkrtz(a, b);
  return __builtin_bit_cast(uint32_t, h);
}

// counted-vmcnt phase boundary (attn only)
#define WAIT4_BAR()  do { asm volatile("s_waitcnt vmcnt(4)" ::: "memory"); \
                          __builtin_amdgcn_sched_barrier(0);               \
                          __builtin_amdgcn_s_barrier();                    \
                          __builtin_amdgcn_sched_barrier(0); } while (0)
#define WAIT0_BAR()  do { asm volatile("s_waitcnt vmcnt(0)" ::: "memory"); \
                          __builtin_amdgcn_sched_barrier(0);               \
                          __builtin_amdgcn_s_barrier();                    \
                          __builtin_amdgcn_sched_barrier(0); } while (0)
#define POST_BAR()   do { __builtin_amdgcn_s_barrier();                    \
                          __builtin_amdgcn_sched_barrier(0); } while (0)

// ---------------- fused fp32 -> fp16 conversion (x, w_qkv, w_out -> contiguous dst) ----
#define N4_X   (MROWS*D_MODEL/4)
#define N4_WQ  (3*D_MODEL*D_MODEL/4)
#define N4_WO  (D_MODEL*D_MODEL/4)
#define N4_TOT (N4_X+N4_WQ+N4_WO)

__global__ __launch_bounds__(256) void k_cvt3(const float* __restrict__ x,
                                              const float* __restrict__ wq,
                                              const float* __restrict__ wo,
                                              half_t* __restrict__ dst) {
  for (int i = blockIdx.x * 256 + threadIdx.x; i < N4_TOT; i += 2048 * 256) {
    const float* s;
    int j = i;
    if (j < N4_X) { s = x; }
    else if (j < N4_X + N4_WQ) { s = wq; j -= N4_X; }
    else { s = wo; j -= N4_X + N4_WQ; }
    float4 v = reinterpret_cast<const float4*>(s)[j];
    half4 o = {(_Float16)v.x, (_Float16)v.y, (_Float16)v.z, (_Float16)v.w};
    *reinterpret_cast<half4*>(dst + (size_t)i * 4) = o;
  }
}

// ---------------- GEMM common geometry: 128x128 tile, BK=64, swizzled LDS ----------
// LDS element (r,c) of a [128][64] half tile stored at r*64 + ((c>>3)^(r&7))*8 + (c&7).
// Staged via global_load_lds with pre-swizzled SOURCE chunk (linear LDS dest).
// PMC-verified: SQ_LDS_BANK_CONFLICT = 0 (r10).
#define BM 128
#define BN 128
#define BK 64
#define NTK (D_MODEL / BK)   // 16

// ---------------- GEMM1: qkv = x @ w_qkv^T + b, scatter to Q/K/VT ----------------
__global__ __launch_bounds__(256) void k_gemm_qkv(
    const half_t* __restrict__ A,    // [8192][1024]
    const half_t* __restrict__ W,    // [3072][1024]
    const float*  __restrict__ bias, // [3072]
    half_t* __restrict__ Qo,         // [64][2048][64]
    half_t* __restrict__ Ko,         // [64][2048][64]
    half_t* __restrict__ VTo)        // [64][64][2048]
{
  constexpr int K = D_MODEL;
  __shared__ __align__(16) half_t As[BM * BK];
  __shared__ __align__(16) half_t Bs[BN * BK];
  const int tid = threadIdx.x;
  const int wid = tid >> 6, lane = tid & 63;
  const int wr = wid >> 1, wc = wid & 1;
  const int lg = lane >> 4, lq = lane & 15;
  const int m0 = blockIdx.x * BM, n0 = blockIdx.y * BN;   // natural grid (L2-friendly)

  f32x4 acc[4][4] = {};

  // staging: instr i (0..3) covers rows i*32+(tid>>3), chunk tid&7 (source pre-swizzled)
  const int srow = tid >> 3;               // 0..31
  const int swc  = ((tid & 7) ^ (srow & 7)) * 8;   // swizzled source col (halfs)
  const half_t* Ag = A + (size_t)(m0 + srow) * K + swc;
  const half_t* Wg = W + (size_t)(n0 + srow) * K + swc;

  for (int kt = 0; kt < NTK; ++kt) {
    __syncthreads();                       // all reads of previous tile done
#pragma unroll
    for (int i = 0; i < 4; ++i) {
      g2l16(Ag + (size_t)(i * 32) * K + kt * BK, &As[i * 2048 + wid * 512]);
      g2l16(Wg + (size_t)(i * 32) * K + kt * BK, &Bs[i * 2048 + wid * 512]);
    }
    __syncthreads();                       // compiler drains vmcnt(0) before barrier

    half8 af[2][4], bf[2][4];
#pragma unroll
    for (int ks = 0; ks < 2; ++ks) {
      const int cs = ((ks * 4 + lg) ^ (lq & 7)) * 8;
#pragma unroll
      for (int mt = 0; mt < 4; ++mt)
        af[ks][mt] = *(const half8*)(&As[(wr * 64 + mt * 16 + lq) * 64 + cs]);
#pragma unroll
      for (int nt = 0; nt < 4; ++nt)
        bf[ks][nt] = *(const half8*)(&Bs[(wc * 64 + nt * 16 + lq) * 64 + cs]);
    }
#pragma unroll
    for (int ks = 0; ks < 2; ++ks)
#pragma unroll
      for (int mt = 0; mt < 4; ++mt)
#pragma unroll
        for (int nt = 0; nt < 4; ++nt)
          acc[mt][nt] = __builtin_amdgcn_mfma_f32_16x16x32_f16(af[ks][mt], bf[ks][nt], acc[mt][nt], 0, 0, 0);
  }

  const int sec   = n0 >> 10;
  const int csec0 = n0 & 1023;
#pragma unroll
  for (int mt = 0; mt < 4; ++mt) {
#pragma unroll
    for (int nt = 0; nt < 4; ++nt) {
      const int n  = n0 + wc * 64 + nt * 16 + lq;
      const float bv = bias[n];
      const int c = csec0 + wc * 64 + nt * 16 + lq;
      const int h = c >> 6, d = c & 63;
#pragma unroll
      for (int r = 0; r < 4; ++r) {
        const int m = m0 + wr * 64 + mt * 16 + lg * 4 + r;
        const int b = m >> 11, s = m & 2047;
        const half_t val = (half_t)(acc[mt][nt][r] + bv);
        const int bhh = (b << 4) + h;
        if (sec == 0)      Qo[((size_t)bhh * SEQ + s) * HDIM + d] = val;
        else if (sec == 1) Ko[((size_t)bhh * SEQ + s) * HDIM + d] = val;
        else               VTo[((size_t)bhh * HDIM + d) * SEQ + s] = val;
      }
    }
  }
}

// ---------------- flash attention (causal), balanced pairs + counted-vmcnt dbuf ----
__global__ __launch_bounds__(256) void k_attn(
    const half_t* __restrict__ Q,   // [64][2048][64]
    const half_t* __restrict__ Kt,  // [64][2048][64]
    const half_t* __restrict__ Vt,  // [64][64][2048]  (V transposed)
    half_t* __restrict__ O)         // [8192][1024]
{
  const int n    = blockIdx.x;                  // 0..511
  const int bh   = (n & 7) * 8 + ((n >> 3) & 7);// head-block: 8 heads per XCD
  const int pg   = n >> 6;                      // 0..7 pair-group
  const int wave = threadIdx.x >> 6, lane = threadIdx.x & 63;
  const int ql   = lane & 31, hi = lane >> 5;
  const int tid  = threadIdx.x;

  __shared__ __align__(16) half_t KS[2][64 * 64];
  __shared__ __align__(16) half_t VS[2][64 * 64];

  const half_t* Qh = Q  + (size_t)bh * SEQ * HDIM;
  const half_t* Kh = Kt + (size_t)bh * SEQ * HDIM;
  const half_t* Vh = Vt + (size_t)bh * HDIM * SEQ;
  const int bb = bh >> 4, hh = bh & 15;

  const int sr0  = tid >> 3;                    // 0..31
  const int sc16 = tid & 7;
  const int sw8  = (sc16 ^ (sr0 & 7)) << 3;     // swizzled chunk offset (halfs)
  const size_t ksrc = (size_t)sr0 * HDIM + sw8;
  const size_t vsrc = (size_t)sr0 * SEQ  + sw8;
  const int xw = ql & 7;                        // read-side row XOR key

  auto stageKV = [&](int kt, int buf) {
    const half_t* kg = Kh + (size_t)kt * 64 * HDIM + ksrc;
    const half_t* vg = Vh + kt * 64 + vsrc;
    g2l16(kg,                    &KS[buf][wave * 512]);
    g2l16(kg + 32 * HDIM,        &KS[buf][2048 + wave * 512]);
    g2l16(vg,                    &VS[buf][wave * 512]);
    g2l16(vg + (size_t)32 * SEQ, &VS[buf][2048 + wave * 512]);
  };

  for (int ph = 0; ph < 2; ++ph) {
    const int j   = ph ? 63 - (pg * 4 + wave) : pg * 4 + wave;   // q-tile (32 rows)
    const int NT  = ph ? 32 - 2 * pg : 2 * pg + 2;               // block-uniform, >=2
    const int ktd = j >> 1;                                      // my last k-tile
    const int qg  = j * 32 + ql;                                 // my q-row

    half8 qf[4];
    {
      const half_t* Qp = Qh + (size_t)qg * HDIM + hi * 8;
      const _Float16 qs = (_Float16)0.125f;
#pragma unroll
      for (int kk = 0; kk < 4; ++kk) {
        half8 t = *(const half8*)(Qp + kk * 16);
        qf[kk] = t * qs;
      }
    }

    f32x16 acc[2] = {};
    float mrun = -1e30f, lrun = 0.f;

    stageKV(0, 0);
    stageKV(1, 1);

    int cur = 0;
    for (int kt = 0; kt < NT; ++kt) {
      if (kt + 1 < NT) WAIT4_BAR(); else WAIT0_BAR();

      if (kt <= ktd) {
        f32x16 sc[2] = {};
        const half_t* Kl = &KS[cur][0];
#pragma unroll
        for (int kk = 0; kk < 4; ++kk) {
          const int c = ((kk * 2 + hi) ^ xw) << 3;
          half8 k0 = *(const half8*)(Kl + ql * 64 + c);
          half8 k1 = *(const half8*)(Kl + (ql + 32) * 64 + c);
          sc[0] = __builtin_amdgcn_mfma_f32_32x32x16_f16(k0, qf[kk], sc[0], 0, 0, 0);
          sc[1] = __builtin_amdgcn_mfma_f32_32x32x16_f16(k1, qf[kk], sc[1], 0, 0, 0);
        }

        half8 vf[2][4];
        const half_t* Vl = &VS[cur][0];
#pragma unroll
        for (int dt = 0; dt < 2; ++dt)
#pragma unroll
          for (int ks = 0; ks < 4; ++ks) {
            const int c = ((ks * 2 + hi) ^ xw) << 3;
            vf[dt][ks] = *(const half8*)(Vl + (dt * 32 + ql) * 64 + c);
          }

        if (kt == ktd) {
#pragma unroll
          for (int t = 0; t < 2; ++t)
#pragma unroll
            for (int r = 0; r < 16; ++r) {
              const int kgl = kt * 64 + t * 32 + (r & 3) + 8 * (r >> 2) + 4 * hi;
              sc[t][r] = (kgl > qg) ? -1e30f : sc[t][r];
            }
        }

        float m0 = -1e30f, m1 = -1e30f, m2 = -1e30f, m3 = -1e30f;
#pragma unroll
        for (int t = 0; t < 2; ++t)
#pragma unroll
          for (int r = 0; r < 16; r += 4) {
            m0 = fmaxf(m0, sc[t][r]);     m1 = fmaxf(m1, sc[t][r + 1]);
            m2 = fmaxf(m2, sc[t][r + 2]); m3 = fmaxf(m3, sc[t][r + 3]);
          }
        float mx = fmaxf(fmaxf(m0, m1), fmaxf(m2, m3));
        mx = fmaxf(mx, __shfl_xor(mx, 32, 64));

        // T13 defer-max: only rescale when the running max grew by >8.
        if (!__all(mx - mrun <= 8.f)) {
          const float mnew = fmaxf(mrun, mx);
          const float alpha = __expf(mrun - mnew);
          mrun = mnew;
          lrun *= alpha;
          acc[0] *= alpha;
          acc[1] *= alpha;
        }

        float s0 = 0.f, s1 = 0.f, s2 = 0.f, s3 = 0.f;
#pragma unroll
        for (int t = 0; t < 2; ++t)
#pragma unroll
          for (int r = 0; r < 16; r += 4) {
            sc[t][r]     = __expf(sc[t][r]     - mrun); s0 += sc[t][r];
            sc[t][r + 1] = __expf(sc[t][r + 1] - mrun); s1 += sc[t][r + 1];
            sc[t][r + 2] = __expf(sc[t][r + 2] - mrun); s2 += sc[t][r + 2];
            sc[t][r + 3] = __expf(sc[t][r + 3] - mrun); s3 += sc[t][r + 3];
          }
        float lsum = (s0 + s1) + (s2 + s3);
        lsum += __shfl_xor(lsum, 32, 64);
        lrun += lsum;

#pragma unroll
        for (int ks = 0; ks < 4; ++ks) {
          const int t  = ks >> 1;
          const int r0 = (ks & 1) * 8;
          const uint32_t a0 = pk16(sc[t][r0 + 0], sc[t][r0 + 1]);
          const uint32_t a1 = pk16(sc[t][r0 + 2], sc[t][r0 + 3]);
          const uint32_t a2 = pk16(sc[t][r0 + 4], sc[t][r0 + 5]);
          const uint32_t a3 = pk16(sc[t][r0 + 6], sc[t][r0 + 7]);
          const uint32_t snd0 = hi ? a0 : a2;
          const uint32_t snd1 = hi ? a1 : a3;
          const uint32_t rc0 = (uint32_t)__shfl_xor((int)snd0, 32, 64);
          const uint32_t rc1 = (uint32_t)__shfl_xor((int)snd1, 32, 64);
          union { uint32_t u[4]; half8 h; } fu;
          fu.u[0] = hi ? rc0 : a0;
          fu.u[1] = hi ? rc1 : a1;
          fu.u[2] = hi ? a2  : rc0;
          fu.u[3] = hi ? a3  : rc1;
          acc[0] = __builtin_amdgcn_mfma_f32_32x32x16_f16(vf[0][ks], fu.h, acc[0], 0, 0, 0);
          acc[1] = __builtin_amdgcn_mfma_f32_32x32x16_f16(vf[1][ks], fu.h, acc[1], 0, 0, 0);
        }
      }

      POST_BAR();
      if (kt + 2 < NT) stageKV(kt + 2, cur);
      cur ^= 1;
    }

    const float inv = 1.0f / lrun;
    half_t* Orow = O + ((size_t)bb * SEQ + qg) * D_MODEL + hh * HDIM + hi * 4;
#pragma unroll
    for (int dt = 0; dt < 2; ++dt)
#pragma unroll
      for (int g = 0; g < 4; ++g) {
        half4 o;
#pragma unroll
        for (int jj = 0; jj < 4; ++jj) o[jj] = (_Float16)(acc[dt][g * 4 + jj] * inv);
        *(half4*)(Orow + dt * 32 + g * 8) = o;
      }
  }
}

// ---------------- GEMM2: out = AO @ w_out^T + b_out (fp32 out), 128^2 BK=64 ----------
__global__ __launch_bounds__(256) void k_gemm_out(
    const half_t* __restrict__ A,
    const half_t* __restrict__ W,
    const float*  __restrict__ bias,
    float* __restrict__ C)
{
  constexpr int K = D_MODEL;
  __shared__ __align__(16) half_t As[BM * BK];
  __shared__ __align__(16) half_t Bs[BN * BK];
  const int tid = threadIdx.x;
  const int wid = tid >> 6, lane = tid & 63;
  const int wr = wid >> 1, wc = wid & 1;
  const int lg = lane >> 4, lq = lane & 15;
  const int m0 = blockIdx.x * BM, n0 = blockIdx.y * BN;   // natural grid

  f32x4 acc[4][4] = {};
  const int srow = tid >> 3;
  const int swc  = ((tid & 7) ^ (srow & 7)) * 8;
  const half_t* Ag = A + (size_t)(m0 + srow) * K + swc;
  const half_t* Wg = W + (size_t)(n0 + srow) * K + swc;

  for (int kt = 0; kt < NTK; ++kt) {
    __syncthreads();
#pragma unroll
    for (int i = 0; i < 4; ++i) {
      g2l16(Ag + (size_t)(i * 32) * K + kt * BK, &As[i * 2048 + wid * 512]);
      g2l16(Wg + (size_t)(i * 32) * K + kt * BK, &Bs[i * 2048 + wid * 512]);
    }
    __syncthreads();

    half8 af[2][4], bf[2][4];
#pragma unroll
    for (int ks = 0; ks < 2; ++ks) {
      const int cs = ((ks * 4 + lg) ^ (lq & 7)) * 8;
#pragma unroll
      for (int mt = 0; mt < 4; ++mt)
        af[ks][mt] = *(const half8*)(&As[(wr * 64 + mt * 16 + lq) * 64 + cs]);
#pragma unroll
      for (int nt = 0; nt < 4; ++nt)
        bf[ks][nt] = *(const half8*)(&Bs[(wc * 64 + nt * 16 + lq) * 64 + cs]);
    }
#pragma unroll
    for (int ks = 0; ks < 2; ++ks)
#pragma unroll
      for (int mt = 0; mt < 4; ++mt)
#pragma unroll
        for (int nt = 0; nt < 4; ++nt)
          acc[mt][nt] = __builtin_amdgcn_mfma_f32_16x16x32_f16(af[ks][mt], bf[ks][nt], acc[mt][nt], 0, 0, 0);
  }

#pragma unroll
  for (int mt = 0; mt < 4; ++mt) {
#pragma unroll
    for (int nt = 0; nt < 4; ++nt) {
      const int n = n0 + wc * 64 + nt * 16 + lq;
      const float bv = bias[n];
#pragma unroll
      for (int r = 0; r < 4; ++r) {
        const int m = m0 + wr * 64 + mt * 16 + lg * 4 + r;
        C[(size_t)m * D_MODEL + n] = acc[mt][nt][r] + bv;
      }
    }
  }
}

// ---------------- launch ----------------
extern "C" void kernel_launch(void* const* d_in, const int* in_sizes, int n_in,
                              void* d_out, int out_size, void* d_ws, size_t ws_size,
                              hipStream_t stream) {
  const float* x    = (const float*)d_in[0];
  const float* wqkv = (const float*)d_in[1];
  const float* bqkv = (const float*)d_in[2];
  const float* wout = (const float*)d_in[3];
  const float* bout = (const float*)d_in[4];
  float* out = (float*)d_out;

  char* ws = (char*)d_ws;
  half_t* xb  = (half_t*)ws; ws += (size_t)MROWS * D_MODEL * 2;
  half_t* wqb = (half_t*)ws; ws += (size_t)3 * D_MODEL * D_MODEL * 2;
  half_t* wob = (half_t*)ws; ws += (size_t)D_MODEL * D_MODEL * 2;
  half_t* Qb  = (half_t*)ws; ws += (size_t)NBH * SEQ * HDIM * 2;
  half_t* Kb  = (half_t*)ws; ws += (size_t)NBH * SEQ * HDIM * 2;
  half_t* Vb  = (half_t*)ws; ws += (size_t)NBH * SEQ * HDIM * 2;
  half_t* AO  = (half_t*)ws; ws += (size_t)MROWS * D_MODEL * 2;

  // xb/wqb/wob are contiguous -> one fused conversion kernel
  k_cvt3<<<2048, 256, 0, stream>>>(x, wqkv, wout, xb);

  k_gemm_qkv<<<dim3(MROWS / BM, 3 * D_MODEL / BN), 256, 0, stream>>>(xb, wqb, bqkv, Qb, Kb, Vb);
  k_attn<<<dim3(512), 256, 0, stream>>>(Qb, Kb, Vb, AO);
  k_gemm_out<<<dim3(MROWS / BM, D_MODEL / BN), 256, 0, stream>>>(AO, wob, bout, out);
}